// Round 13
// baseline (173.261 us; speedup 1.0000x reference)
//
#include <hip/hip_runtime.h>

#define B_ 8
#define M_ 32
#define C_ 512
#define H_ 64
#define W_ 64
#define HW 4096
#define NKT 16
#define KC 32
// gcm tile
#define TW 4
#define TH 2
#define NPOS 8
#define PW 6
#define PH 4
#define NPM 24
// padded m grid
#define HP 66
#define WP 66
#define HPWP (HP*WP)

typedef __attribute__((ext_vector_type(8))) short short8;
typedef __attribute__((ext_vector_type(4))) float float4v;

static __device__ __forceinline__ unsigned pk_bf16(float lo, float hi) {
    unsigned r;
    asm("v_cvt_pk_bf16_f32 %0, %1, %2" : "=v"(r) : "v"(lo), "v"(hi));
    return r;
}

static __device__ __forceinline__ void load_lds16(const short* g, short* l) {
    __builtin_amdgcn_global_load_lds((const __attribute__((address_space(1))) void*)g,
                                     (__attribute__((address_space(3))) void*)l, 16, 0, 0);
}

// ---------- zero the norm-accumulator buffers (re-run every launch) ----------
__global__ void zero_norms(float* __restrict__ p) {
    int i = blockIdx.x * 256 + threadIdx.x;          // 160*256*4 = 163840 floats
    ((float4v*)p)[i] = (float4v){0.f, 0.f, 0.f, 0.f};
}

// ---------- prep v8: v4 + h-pair + both-imgs per thread (4 loads in flight) ----------
// blocks 0..511   : q (pr = g>>7 of 4,  h2 = (g>>2)&31, ktg = g&3)
// blocks 512..2559: m (pr of 16, h2, ktg)
// LDS slot(row,img,w,cpair) = row*2176 + img*1088 + w*17 + cpair
__global__ __launch_bounds__(512, 8)
void prep_kernel(const float* __restrict__ Q, const float* __restrict__ Mb,
                 short* __restrict__ qT, short* __restrict__ mT,
                 float* __restrict__ nq, float* __restrict__ nm) {
    __shared__ unsigned buf[2][4352];   // 2 x 17.4 KB

    const int tid = threadIdx.x;
    const bool isq = (blockIdx.x < 512);
    const int g  = isq ? (int)blockIdx.x : (int)blockIdx.x - 512;
    const int pr  = g >> 7;
    const int h2  = (g >> 2) & 31;
    const int ktg = g & 3;
    const float* base = (isq ? Q : Mb) + (size_t)(pr * 2) * C_ * HW;

    // load/LDS-write roles: (w4, row) x cpair; each thread handles both images
    const int lw4 = tid & 15, lrow = (tid >> 4) & 1, cpair = tid >> 5;   // cpair 0..15
    const float* lsrc0 = base + (size_t)(ktg * 128 + cpair * 2) * HW
                       + (h2 * 2 + lrow) * W_ + lw4 * 4;
    // gather/store roles
    const int ckq = tid & 3, rimg = (tid >> 2) & 1, rw = tid >> 3;       // rw 0..63
    float4v A0, A1, A2, A3;
    float4v sA = {0.f,0.f,0.f,0.f}, sB = sA;

#define LOADP(ch) { const float* p_ = lsrc0 + (size_t)(ch) * 32 * HW; \
    A0 = *(const float4v*)(p_); \
    A1 = *(const float4v*)(p_ + HW); \
    A2 = *(const float4v*)(p_ + (size_t)C_ * HW); \
    A3 = *(const float4v*)(p_ + (size_t)C_ * HW + HW); }

#define WRITEP(bs) { \
    sA += A0 * A0 + A1 * A1;  sB += A2 * A2 + A3 * A3; \
    unsigned* b_ = &buf[bs][lrow * 2176 + lw4 * 68 + cpair]; \
    _Pragma("unroll") \
    for (int j = 0; j < 4; ++j) { \
        b_[j * 17]        = pk_bf16(A0[j], A1[j]); \
        b_[1088 + j * 17] = pk_bf16(A2[j], A3[j]); } }

#define STOREP(ch, bs) { \
    const int kt_ = ktg * 4 + (ch); \
    _Pragma("unroll") \
    for (int sr = 0; sr < 2; ++sr) { \
        const unsigned* rp = &buf[bs][sr * 2176 + rimg * 1088 + rw * 17 + ckq * 4]; \
        union { unsigned u[4]; short8 s; } o_; \
        o_.u[0] = rp[0]; o_.u[1] = rp[1]; o_.u[2] = rp[2]; o_.u[3] = rp[3]; \
        short* dst_; \
        if (isq) dst_ = qT + (((size_t)kt_ * HW + (h2 * 2 + sr) * 64 + rw) * B_ \
                              + pr * 2 + rimg) * KC + ckq * 8; \
        else     dst_ = mT + (((size_t)kt_ * HPWP + (size_t)(h2 * 2 + sr + 1) * WP + rw + 1) * M_ \
                              + pr * 2 + rimg) * KC + ckq * 8; \
        *(short8*)dst_ = o_.s; } }

    LOADP(0); WRITEP(0); __syncthreads();
    LOADP(1); STOREP(0, 0); WRITEP(1); __syncthreads();
    LOADP(2); STOREP(1, 1); WRITEP(0); __syncthreads();
    LOADP(3); STOREP(2, 0); WRITEP(1); __syncthreads();
    STOREP(3, 1);
    // norm partials -> buf0 (disjoint from buf1 being stored)
    {
        float* red = (float*)&buf[0][0];   // 4096 f32 = 16 KB
        *(float4v*)&red[((lrow * 2 + 0) * 16 + cpair) * 64 + lw4 * 4] = sA;
        *(float4v*)&red[((lrow * 2 + 1) * 16 + cpair) * 64 + lw4 * 4] = sB;
    }
    __syncthreads();

    if (tid < 256) {
        const float* red = (const float*)&buf[0][0];
        int row = tid >> 7, im_ = (tid >> 6) & 1, w = tid & 63;
        float t = 0.f;
        #pragma unroll
        for (int cp = 0; cp < 16; ++cp) t += red[((row * 2 + im_) * 16 + cp) * 64 + w];
        atomicAdd(&(isq ? nq : nm)[(size_t)(pr * 2 + im_) * HW + (h2 * 2 + row) * 64 + w], t);
    }

    // ---- m-blocks: zero halo-ring slices (2 rows, this ktg, its pr 128B slice) ----
    if (!isq) {
        short8 z = (short8){0, 0, 0, 0, 0, 0, 0, 0};
        if (tid < 128) {                     // cols 0 & 65 of rows h2*2+1, h2*2+2
            int e = tid & 7, kk = (tid >> 3) & 3, rr = (tid >> 5) & 1, cc = tid >> 6;
            int kt = ktg * 4 + kk;
            size_t pos2 = (size_t)(h2 * 2 + 1 + rr) * WP + (cc ? 65 : 0);
            *(short8*)(mT + ((size_t)kt * HPWP + pos2) * (M_ * KC) + pr * 64 + e * 8) = z;
        }
        if (h2 == 0 || h2 == 31) {           // full rows 0 / 65 for this ktg
            int row = (h2 == 0) ? 0 : 65;
            for (int j = tid; j < 66 * 4 * 8; j += 512) {
                int e = j & 7, kk = (j >> 3) & 3, cell = j >> 5;
                int kt = ktg * 4 + kk;
                *(short8*)(mT + ((size_t)kt * HPWP + (size_t)row * WP + cell) * (M_ * KC)
                           + pr * 64 + e * 8) = z;
            }
        }
    }
#undef LOADP
#undef WRITEP
#undef STOREP
}

// ---------- gcm v2: 4x2 tile, 512 blocks (all CUs), rsqrt epilogue (unchanged) ----------
__global__ __launch_bounds__(512)
void gcm_kernel(const short* __restrict__ qT, const short* __restrict__ mT,
                const float* __restrict__ nq, const float* __restrict__ nm,
                float* __restrict__ out) {
    __shared__ __align__(16) short m_lds[NPM * M_ * KC];   // 48 KB
    __shared__ __align__(16) short q_lds[NPOS * 16 * KC];  // 8 KB

    const int tid = threadIdx.x;
    const int bx = blockIdx.x & 15, by = blockIdx.x >> 4;   // by 0..31
    const int w0 = bx * TW, h0 = by * TH;
    const int wid = tid >> 6, lane = tid & 63;
    const int lw = wid & 3, lh = wid >> 2;                  // lh 0..1
    const int col = lane & 15, kg = lane >> 4;
    const int mypos = lh * TW + lw;
    const int gh = h0 + lh, gw = w0 + lw;

    {
        short8 z = (short8){0, 0, 0, 0, 0, 0, 0, 0};
        *(short8*)&q_lds[tid * 8] = z;
    }

    float4v acc[9][2];
    #pragma unroll
    for (int d = 0; d < 9; ++d)
        #pragma unroll
        for (int hf = 0; hf < 2; ++hf)
            acc[d][hf] = (float4v){0.f, 0.f, 0.f, 0.f};

    for (int kt = 0; kt < NKT; ++kt) {
        __syncthreads();
        if (tid < 256) {
            int chunk = tid & 3, b = (tid >> 2) & 7, pidx = tid >> 5;   // pidx 0..7
            int qh = h0 + (pidx >> 2), qw = w0 + (pidx & 3);
            const short* src = qT + (((size_t)kt * HW + qh * W_ + qw) * B_ + b) * KC + chunk * 8;
            *(short8*)&q_lds[pidx * 512 + b * KC + chunk * 8] = *(const short8*)src;
        }
        for (int j = wid; j < NPM * 2; j += 8) {
            int pm = j >> 1, half = j & 1;
            int ph = pm / PW, pw = pm % PW;
            size_t pos2 = (size_t)(h0 + ph) * WP + (w0 + pw);
            const short* gsrc = mT + ((size_t)kt * HPWP + pos2) * (M_ * KC)
                              + half * 512 + (size_t)lane * 8;
            short* ldst = m_lds + pm * 1024 + half * 512;
            load_lds16(gsrc, ldst);
        }
        __syncthreads();
        short8 aq = *(const short8*)&q_lds[mypos * 512 + col * KC + kg * 8];
        #pragma unroll
        for (int dh = 0; dh < 3; ++dh)
            #pragma unroll
            for (int dw = 0; dw < 3; ++dw) {
                const int pm = (lh + dh) * PW + (lw + dw);
                #pragma unroll
                for (int hf = 0; hf < 2; ++hf) {
                    short8 bm = *(const short8*)&m_lds[pm * 1024 + (hf * 16 + col) * KC + kg * 8];
                    acc[dh * 3 + dw][hf] =
                        __builtin_amdgcn_mfma_f32_16x16x32_bf16(aq, bm, acc[dh * 3 + dw][hf], 0, 0, 0);
                }
            }
    }

    float iq[4];
    #pragma unroll
    for (int r = 0; r < 4; ++r) {
        float ss = nq[(size_t)((kg & 1) * 4 + r) * HW + gh * W_ + gw];
        iq[r] = 1.0f / fmaxf(sqrtf(ss), 1e-12f);
    }
    float im[2][9];
    #pragma unroll
    for (int dh = 0; dh < 3; ++dh)
        #pragma unroll
        for (int dw = 0; dw < 3; ++dw) {
            int hh = min(63, max(0, gh + dh - 1));
            int ww = min(63, max(0, gw + dw - 1));
            #pragma unroll
            for (int hf = 0; hf < 2; ++hf) {
                float ss = nm[(size_t)(hf * 16 + col) * HW + hh * W_ + ww];
                im[hf][dh * 3 + dw] = 1.0f / fmaxf(sqrtf(ss), 1e-12f);
            }
        }
    float res[4];
    #pragma unroll
    for (int r = 0; r < 4; ++r) {
        float v0 = -1e30f, v1 = -1e30f;
        #pragma unroll
        for (int d = 0; d < 9; ++d) {
            v0 = fmaxf(v0, acc[d][0][r] * im[0][d]);
            v1 = fmaxf(v1, acc[d][1][r] * im[1][d]);
        }
        res[r] = fmaxf(v0 * iq[r], 0.f) + fmaxf(v1 * iq[r], 0.f);
    }
    #pragma unroll
    for (int mask = 1; mask < 16; mask <<= 1)
        #pragma unroll
        for (int r = 0; r < 4; ++r)
            res[r] += __shfl_xor(res[r], mask);

    if (col == 0 && kg < 2) {
        #pragma unroll
        for (int r = 0; r < 4; ++r) {
            int b = kg * 4 + r;
            out[(size_t)b * HW + gh * W_ + gw] = 1.0f - res[r] * (1.0f / M_);
        }
    }
}

extern "C" void kernel_launch(void* const* d_in, const int* in_sizes, int n_in,
                              void* d_out, int out_size, void* d_ws, size_t ws_size,
                              hipStream_t stream) {
    const float* Q  = (const float*)d_in[0];
    const float* Mb = (const float*)d_in[1];
    float* out = (float*)d_out;

    const size_t MT_SHORTS = (size_t)NKT * HPWP * M_ * KC;   // 71,368,704
    const size_t QT_SHORTS = (size_t)NKT * HW * B_ * KC;     // 16,777,216
    short* mT = (short*)d_ws;
    short* qT = mT + MT_SHORTS;
    float* nq = (float*)(qT + QT_SHORTS);
    float* nm = nq + B_ * HW;

    zero_norms<<<160, 256, 0, stream>>>(nq);                 // nq+nm contiguous 163840 f32
    prep_kernel<<<2560, 512, 0, stream>>>(Q, Mb, qT, mT, nq, nm);
    gcm_kernel<<<512, 512, 0, stream>>>(qT, mT, nq, nm, out);
}